// Round 1
// baseline (2743.381 us; speedup 1.0000x reference)
//
#include <hip/hip_runtime.h>

#define HID 51
#define NG 204      // 4*HID
#define TLEN 1024

__device__ __forceinline__ float frcp(float v)  { return __builtin_amdgcn_rcpf(v); }
__device__ __forceinline__ float sigm(float v)  { return frcp(1.0f + __expf(-v)); }
__device__ __forceinline__ float tanh_f(float v){ float e = __expf(2.0f * v); return 1.0f - 2.0f * frcp(e + 1.0f); }

__global__ __launch_bounds__(256, 2)
void lstm2_kernel(const float* __restrict__ x,
                  const float* __restrict__ W_ih0,
                  const float* __restrict__ W_hh0,
                  const float* __restrict__ b_ih0,
                  const float* __restrict__ b_hh0,
                  const float* __restrict__ W_ih1,
                  const float* __restrict__ W_hh1,
                  const float* __restrict__ b_ih1,
                  const float* __restrict__ b_hh1,
                  const float* __restrict__ W_lin,
                  const float* __restrict__ b_lin,
                  float* __restrict__ out)
{
    const int b   = blockIdx.x;
    const int tid = threadIdx.x;

    __shared__ __align__(16) float h0s[52];
    __shared__ __align__(16) float h1s[52];
    __shared__ float gs[NG];

    // Per-lane persistent weight registers (lane = gate index, 204 active lanes).
    float w0[52], wi1[52], wh1[52];
    float bsum0 = 0.f, bsum1 = 0.f, wih0 = 0.f;
    const bool is_gate = (tid < NG);
    if (is_gate) {
        #pragma unroll
        for (int j = 0; j < HID; ++j) w0[j]  = W_hh0[tid * HID + j];
        #pragma unroll
        for (int j = 0; j < HID; ++j) wi1[j] = W_ih1[tid * HID + j];
        #pragma unroll
        for (int j = 0; j < HID; ++j) wh1[j] = W_hh1[tid * HID + j];
        bsum0 = b_ih0[tid] + b_hh0[tid];
        bsum1 = b_ih1[tid] + b_hh1[tid];
        wih0  = W_ih0[tid];          // [204,1] -> column 0
    }
    w0[51] = 0.f; wi1[51] = 0.f; wh1[51] = 0.f;   // pad so float4 tail is harmless
    const float wlin = (tid < HID) ? W_lin[tid] : 0.f;
    const float blin = b_lin[0];

    // gate type: [0,51)=i sigmoid, [51,102)=f sigmoid, [102,153)=g tanh, [153,204)=o sigmoid
    const bool is_tanh_gate = (tid >= 2 * HID && tid < 3 * HID);

    float c0 = 0.f, c1 = 0.f;
    if (tid < 52) { h0s[tid] = 0.f; h1s[tid] = 0.f; }
    __syncthreads();

    const float* xrow = x   + (size_t)b * TLEN;
    float*       orow = out + (size_t)b * TLEN;
    float x_cur = xrow[0];

    for (int t = 0; t < TLEN; ++t) {
        float x_nxt = xrow[(t + 1 < TLEN) ? t + 1 : t];   // prefetch next scalar input

        // ---- P1: layer-0 gate pre-activations + activation
        if (is_gate) {
            float acc = fmaf(x_cur, wih0, bsum0);
            #pragma unroll
            for (int q = 0; q < 13; ++q) {
                float4 hv = *reinterpret_cast<const float4*>(&h0s[4 * q]);
                acc = fmaf(hv.x, w0[4 * q + 0], acc);
                acc = fmaf(hv.y, w0[4 * q + 1], acc);
                acc = fmaf(hv.z, w0[4 * q + 2], acc);
                acc = fmaf(hv.w, w0[4 * q + 3], acc);
            }
            gs[tid] = is_tanh_gate ? tanh_f(acc) : sigm(acc);
        }
        __syncthreads();

        // ---- P2: layer-0 cell/hidden update (lanes 0..50)
        if (tid < HID) {
            float gi = gs[tid], gf = gs[HID + tid], gg = gs[2 * HID + tid], go = gs[3 * HID + tid];
            c0 = fmaf(gf, c0, gi * gg);
            h0s[tid] = go * tanh_f(c0);
        }
        __syncthreads();

        // ---- P3: layer-1 gate pre-activations + activation
        if (is_gate) {
            float acc = bsum1;
            #pragma unroll
            for (int q = 0; q < 13; ++q) {
                float4 h0v = *reinterpret_cast<const float4*>(&h0s[4 * q]);
                float4 h1v = *reinterpret_cast<const float4*>(&h1s[4 * q]);
                acc = fmaf(h0v.x, wi1[4 * q + 0], acc);
                acc = fmaf(h0v.y, wi1[4 * q + 1], acc);
                acc = fmaf(h0v.z, wi1[4 * q + 2], acc);
                acc = fmaf(h0v.w, wi1[4 * q + 3], acc);
                acc = fmaf(h1v.x, wh1[4 * q + 0], acc);
                acc = fmaf(h1v.y, wh1[4 * q + 1], acc);
                acc = fmaf(h1v.z, wh1[4 * q + 2], acc);
                acc = fmaf(h1v.w, wh1[4 * q + 3], acc);
            }
            gs[tid] = is_tanh_gate ? tanh_f(acc) : sigm(acc);
        }
        __syncthreads();

        // ---- P4: layer-1 update + projection output
        float part = 0.f;
        if (tid < HID) {
            float gi = gs[tid], gf = gs[HID + tid], gg = gs[2 * HID + tid], go = gs[3 * HID + tid];
            c1 = fmaf(gf, c1, gi * gg);
            float h1 = go * tanh_f(c1);
            h1s[tid] = h1;
            part = h1 * wlin;
        }
        if (tid < 64) {  // wave-0 reduction over 51 partials (rest are 0)
            #pragma unroll
            for (int off = 32; off > 0; off >>= 1)
                part += __shfl_down(part, off, 64);
            if (tid == 0) orow[t] = part + blin;
        }
        __syncthreads();

        x_cur = x_nxt;
    }
}

extern "C" void kernel_launch(void* const* d_in, const int* in_sizes, int n_in,
                              void* d_out, int out_size, void* d_ws, size_t ws_size,
                              hipStream_t stream) {
    const float* x     = (const float*)d_in[0];
    const float* W_ih0 = (const float*)d_in[1];
    const float* W_hh0 = (const float*)d_in[2];
    const float* b_ih0 = (const float*)d_in[3];
    const float* b_hh0 = (const float*)d_in[4];
    const float* W_ih1 = (const float*)d_in[5];
    const float* W_hh1 = (const float*)d_in[6];
    const float* b_ih1 = (const float*)d_in[7];
    const float* b_hh1 = (const float*)d_in[8];
    const float* W_lin = (const float*)d_in[9];
    const float* b_lin = (const float*)d_in[10];
    float* out = (float*)d_out;

    const int B = in_sizes[0] / TLEN;   // x is [B, T] with T = 1024
    lstm2_kernel<<<dim3(B), dim3(256), 0, stream>>>(
        x, W_ih0, W_hh0, b_ih0, b_hh0, W_ih1, W_hh1, b_ih1, b_hh1, W_lin, b_lin, out);
}